// Round 12
// baseline (143.187 us; speedup 1.0000x reference)
//
#include <hip/hip_runtime.h>
#include <hip/hip_bf16.h>

typedef __attribute__((ext_vector_type(8))) __bf16 bf16x8;
typedef __attribute__((ext_vector_type(4))) float f32x4;

#define N_NODES 50000
#define N_EDGES 800000
#define N_TILES 50000            // 16-edge tiles
#define WAVES 4                  // 256-thread blocks
#define TPW 4                    // tiles per wave (2 pairs)
#define NP 2
#define NBLOCKS 3125             // 3125 * 4 * 4 = 50000 exactly

#define XS_OFF 0LL
#define XT_OFF 3200000LL         // 50000*64
#define U_OFF  6400000LL
#define WS_ELEMS 6408192LL       // + 128*64
#define WS_BYTES (WS_ELEMS * 2)

// ---- prep: convert gather tables x_s | x_t | u to bf16 in ws (r9-verified) ----
__global__ void prep_tables(const float* __restrict__ x_s,
                            const float* __restrict__ x_t,
                            const float* __restrict__ ug,
                            __bf16* __restrict__ ws) {
    long long i = (long long)(blockIdx.x * 256 + threadIdx.x) * 8;
    if (i >= WS_ELEMS) return;
    const float* src = (i < XT_OFF) ? (x_s + i)
                     : (i < U_OFF)  ? (x_t + (i - XT_OFF))
                                    : (ug  + (i - U_OFF));
    float4 f0 = *(const float4*)src;
    float4 f1 = *(const float4*)(src + 4);
    bf16x8 o;
    o[0] = (__bf16)f0.x; o[1] = (__bf16)f0.y; o[2] = (__bf16)f0.z; o[3] = (__bf16)f0.w;
    o[4] = (__bf16)f1.x; o[5] = (__bf16)f1.y; o[6] = (__bf16)f1.z; o[7] = (__bf16)f1.w;
    *(bf16x8*)(ws + i) = o;
}

__device__ __forceinline__ void gload16(const void* g, void* l) {
    __builtin_amdgcn_global_load_lds(
        (const __attribute__((address_space(1))) void*)g,
        (__attribute__((address_space(3))) void*)l, 16, 0, 0);
}

template<bool BF>
__global__ __launch_bounds__(256, 2) void edge_mlp_kernel(
    const float* __restrict__ x_s, const float* __restrict__ x_t,
    const int* __restrict__ edge_index, const float* __restrict__ edge_attr,
    const float* __restrict__ ug, const int* __restrict__ batch_e,
    const float* __restrict__ W1, const float* __restrict__ b1,
    const float* __restrict__ W2, const float* __restrict__ b2,
    const __bf16* __restrict__ tbl,
    float* __restrict__ out)
{
    // LDS: 32768 (sW1) + 16384 (sH1 2 slots/wave, swizzled) + 32768 (ring) = 81920
    //      = exactly 2 blocks/CU (163840/2)
    __shared__ __align__(16) unsigned char sW1[32768];        // [n1][k] bf16, 512B rows, XOR-swz
    __shared__ __align__(16) unsigned char sH1[WAVES][2][2048]; // [16e][64n1] bf16, XOR-swz
    __shared__ __align__(16) unsigned char sRing[WAVES][2][4096]; // pair bufs {A,B}

    const int t = threadIdx.x;

    for (int idx = t; idx < 256 * 64; idx += 256) {
        int k = idx >> 6, n = idx & 63;
        *(__bf16*)(sW1 + n * 512 + ((k * 2) ^ ((n & 7) << 4))) = (__bf16)W1[idx];
    }
    __syncthreads();

    const int wave = t >> 6;
    const int lane = t & 63;
    const int l15  = lane & 15;
    const int lk   = lane >> 4;
    const int wxor = (l15 & 7) << 4;

    float bv1[4];
    #pragma unroll
    for (int nf = 0; nf < 4; ++nf) bv1[nf] = b1[nf * 16 + l15];
    f32x4 bias2frag[4];
    #pragma unroll
    for (int mf = 0; mf < 4; ++mf)
        #pragma unroll
        for (int r = 0; r < 4; ++r)
            bias2frag[mf][r] = b2[mf * 16 + lk * 4 + r];

    // ---- W2^T A-fragments in 16 VGPRs (tile-invariant; r10-verified) ----
    bf16x8 aw2[2][4];
    #pragma unroll
    for (int kk2 = 0; kk2 < 2; ++kk2)
        #pragma unroll
        for (int mf = 0; mf < 4; ++mf)
            #pragma unroll
            for (int r = 0; r < 8; ++r)
                aw2[kk2][mf][r] = (__bf16)W2[(kk2 * 32 + lk * 8 + r) * 64 + mf * 16 + l15];

    const int tile_base = (blockIdx.x * WAVES + wave) * TPW;

    int srcs[TPW], tgts[TPW], bgs[TPW];
    int ss_lo[TPW], ss_hi[TPW], tt_lo[TPW], tt_hi[TPW];
    #pragma unroll
    for (int i = 0; i < TPW; ++i) {
        const int e = (tile_base + i) * 16 + l15;
        srcs[i] = edge_index[e];
        tgts[i] = edge_index[N_EDGES + e];
        bgs[i]  = batch_e[e];
    }
    #pragma unroll
    for (int i = 0; i < TPW; ++i) {
        ss_lo[i] = __shfl(srcs[i], lane >> 3);
        ss_hi[i] = __shfl(srcs[i], 8 + (lane >> 3));
        tt_lo[i] = __shfl(tgts[i], lane >> 3);
        tt_hi[i] = __shfl(tgts[i], 8 + (lane >> 3));
    }
    // pre-swizzled source elem offset (r10-verified; rule 21)
    const int swzel = ((((lane & 7) << 4) ^ (((lane >> 3) & 7) << 4)) >> 1);

    // ---- one-tile compute (all indices compile-time; SROA-safe) ----
    auto run_tile = [&](int e, bf16x8 rf0, bf16x8 rf1, bf16x8 rf2, bf16x8 rf3,
                        f32x4 ea0, f32x4 ea1, f32x4 ea2, f32x4 ea3,
                        bf16x8 uf0, bf16x8 uf1, int sl) {
        f32x4 acc[4];
        #pragma unroll
        for (int nf = 0; nf < 4; ++nf)
            acc[nf] = (f32x4){bv1[nf], bv1[nf], bv1[nf], bv1[nf]};
        #pragma unroll
        for (int kk = 0; kk < 8; ++kk) {
            bf16x8 a;
            if      (kk == 0) a = rf0;
            else if (kk == 1) a = rf1;
            else if (kk == 2) a = rf2;
            else if (kk == 3) a = rf3;
            else if (kk == 4) {
                #pragma unroll
                for (int r = 0; r < 4; ++r) { a[r] = (__bf16)ea0[r]; a[4+r] = (__bf16)ea1[r]; }
            } else if (kk == 5) {
                #pragma unroll
                for (int r = 0; r < 4; ++r) { a[r] = (__bf16)ea2[r]; a[4+r] = (__bf16)ea3[r]; }
            } else a = (kk == 6) ? uf0 : uf1;
            #pragma unroll
            for (int nf = 0; nf < 4; ++nf) {
                bf16x8 b = *(const bf16x8*)(sW1 + (nf * 16 + l15) * 512 +
                                            ((kk * 64 + lk * 16) ^ wxor));
                acc[nf] = __builtin_amdgcn_mfma_f32_16x16x32_bf16(a, b, acc[nf], 0, 0, 0);
            }
        }
        // LeakyReLU -> bf16 -> swizzled sH1 slot
        unsigned char* hb = &sH1[wave][sl][0];
        #pragma unroll
        for (int nf = 0; nf < 4; ++nf)
            #pragma unroll
            for (int r = 0; r < 4; ++r) {
                float v = acc[nf][r];
                v = fmaxf(v, 0.1f * v);
                const int row = lk * 4 + r, col = nf * 16 + l15;
                *(__bf16*)(hb + row * 128 + ((col * 2) ^ ((row & 7) << 4))) = (__bf16)v;
            }
        // GEMM2^T
        f32x4 acc2[4];
        #pragma unroll
        for (int mf = 0; mf < 4; ++mf) acc2[mf] = bias2frag[mf];
        #pragma unroll
        for (int kk2 = 0; kk2 < 2; ++kk2) {
            bf16x8 bh = *(const bf16x8*)(hb + l15 * 128 +
                                         ((kk2 * 64 + lk * 16) ^ ((l15 & 7) << 4)));
            #pragma unroll
            for (int mf = 0; mf < 4; ++mf)
                acc2[mf] = __builtin_amdgcn_mfma_f32_16x16x32_bf16(aw2[kk2][mf], bh, acc2[mf], 0, 0, 0);
        }
        float* orow = out + (long long)e * 64;
        #pragma unroll
        for (int mf = 0; mf < 4; ++mf)
            *(f32x4*)&orow[mf * 16 + lk * 4] = acc2[mf];
    };

    if (BF) {
        // ---- prologue: DMA pair 0 (tiles 0,1) ----
        #pragma unroll
        for (int b = 0; b < 2; ++b) {
            unsigned char* rb = &sRing[wave][b][0];
            gload16(tbl + XS_OFF + (long long)ss_lo[b] * 64 + swzel, rb);
            gload16(tbl + XS_OFF + (long long)ss_hi[b] * 64 + swzel, rb + 1024);
            gload16(tbl + XT_OFF + (long long)tt_lo[b] * 64 + swzel, rb + 2048);
            gload16(tbl + XT_OFF + (long long)tt_hi[b] * 64 + swzel, rb + 3072);
        }

        #pragma unroll
        for (int p = 0; p < NP; ++p) {
            const int ia = 2 * p, ib = 2 * p + 1;
            const int eA = (tile_base + ia) * 16 + l15;
            const int eB = (tile_base + ib) * 16 + l15;

            // ---- (1) plain loads for BOTH tiles: ea x8, u x4 (12 VMEM) ----
            const float* peA = edge_attr + (long long)eA * 64 + lk * 8;
            f32x4 eaA0 = *(const f32x4*)(peA);
            f32x4 eaA1 = *(const f32x4*)(peA + 4);
            f32x4 eaA2 = *(const f32x4*)(peA + 32);
            f32x4 eaA3 = *(const f32x4*)(peA + 36);
            const float* peB = edge_attr + (long long)eB * 64 + lk * 8;
            f32x4 eaB0 = *(const f32x4*)(peB);
            f32x4 eaB1 = *(const f32x4*)(peB + 4);
            f32x4 eaB2 = *(const f32x4*)(peB + 32);
            f32x4 eaB3 = *(const f32x4*)(peB + 36);
            const __bf16* puA = tbl + U_OFF + (long long)bgs[ia] * 64 + lk * 8;
            bf16x8 uA0 = *(const bf16x8*)(puA);
            bf16x8 uA1 = *(const bf16x8*)(puA + 32);
            const __bf16* puB = tbl + U_OFF + (long long)bgs[ib] * 64 + lk * 8;
            bf16x8 uB0 = *(const bf16x8*)(puB);
            bf16x8 uB1 = *(const bf16x8*)(puB + 32);
            __builtin_amdgcn_sched_barrier(0);

            // ---- (2) wait for this pair's ring DMA (in-order vmcnt) ----
            // p==0: queue = D0(8) + P(12)            -> vmcnt(12)
            // p==1: queue = D1(8) + S(8) + P(12)     -> vmcnt(20)
            if (p == 0) asm volatile("s_waitcnt vmcnt(12)" ::: "memory");
            else        asm volatile("s_waitcnt vmcnt(20)" ::: "memory");
            __builtin_amdgcn_sched_barrier(0);

            // ---- (3) ring -> regs for both tiles (frees bufs for next DMA) ----
            bf16x8 rA0, rA1, rA2, rA3, rB0, rB1, rB2, rB3;
            {
                const unsigned char* ra = &sRing[wave][0][0];
                const unsigned char* rb = &sRing[wave][1][0];
                const int o0 = l15 * 128 + ((0 * 64 + lk * 16) ^ wxor);
                const int o1 = l15 * 128 + ((1 * 64 + lk * 16) ^ wxor);
                rA0 = *(const bf16x8*)(ra + o0);
                rA1 = *(const bf16x8*)(ra + o1);
                rA2 = *(const bf16x8*)(ra + 2048 + o0);
                rA3 = *(const bf16x8*)(ra + 2048 + o1);
                rB0 = *(const bf16x8*)(rb + o0);
                rB1 = *(const bf16x8*)(rb + o1);
                rB2 = *(const bf16x8*)(rb + 2048 + o0);
                rB3 = *(const bf16x8*)(rb + 2048 + o1);
            }
            asm volatile("s_waitcnt lgkmcnt(0)" ::: "memory");
            __builtin_amdgcn_sched_barrier(0);

            // ---- (4) DMA next pair into the freed bufs ----
            if (p + 1 < NP) {
                #pragma unroll
                for (int b = 0; b < 2; ++b) {
                    const int tn = 2 * (p + 1) + b;
                    unsigned char* rb = &sRing[wave][b][0];
                    gload16(tbl + XS_OFF + (long long)ss_lo[tn] * 64 + swzel, rb);
                    gload16(tbl + XS_OFF + (long long)ss_hi[tn] * 64 + swzel, rb + 1024);
                    gload16(tbl + XT_OFF + (long long)tt_lo[tn] * 64 + swzel, rb + 2048);
                    gload16(tbl + XT_OFF + (long long)tt_hi[tn] * 64 + swzel, rb + 3072);
                }
            }
            __builtin_amdgcn_sched_barrier(0);

            // ---- (5) compute both tiles (scheduler interleaves A and B) ----
            run_tile(eA, rA0, rA1, rA2, rA3, eaA0, eaA1, eaA2, eaA3, uA0, uA1, 0);
            run_tile(eB, rB0, rB1, rB2, rB3, eaB0, eaB1, eaB2, eaB3, uB0, uB1, 1);
        }
    } else {
        // fallback: direct fp32 gathers (r2 structure)
        for (int i = 0; i < TPW; ++i) {
            const int e = (tile_base + i) * 16 + l15;
            const float* pS = x_s + (long long)srcs[i] * 64 + lk * 8;
            const float* pT = x_t + (long long)tgts[i] * 64 + lk * 8;
            const float* pE = edge_attr + (long long)e * 64 + lk * 8;
            const float* pU = ug + (long long)bgs[i] * 64 + lk * 8;
            f32x4 v[8];
            v[0]=*(const f32x4*)pS;      v[1]=*(const f32x4*)(pS+32);
            v[2]=*(const f32x4*)pT;      v[3]=*(const f32x4*)(pT+32);
            v[4]=*(const f32x4*)pE;      v[5]=*(const f32x4*)(pE+32);
            v[6]=*(const f32x4*)pU;      v[7]=*(const f32x4*)(pU+32);
            f32x4 w[8];
            w[0]=*(const f32x4*)(pS+4);  w[1]=*(const f32x4*)(pS+36);
            w[2]=*(const f32x4*)(pT+4);  w[3]=*(const f32x4*)(pT+36);
            w[4]=*(const f32x4*)(pE+4);  w[5]=*(const f32x4*)(pE+36);
            w[6]=*(const f32x4*)(pU+4);  w[7]=*(const f32x4*)(pU+36);
            bf16x8 fr[8];
            #pragma unroll
            for (int c = 0; c < 8; ++c) {
                const int m = (c >> 1) * 2 + (c & 1);  // seg-major order kk
                const int s2 = (c >> 1), h = (c & 1);
                #pragma unroll
                for (int r = 0; r < 4; ++r) {
                    fr[s2 * 2 + h][r]     = (__bf16)v[s2 * 2 + h][r];
                    fr[s2 * 2 + h][4 + r] = (__bf16)w[s2 * 2 + h][r];
                }
                (void)m;
            }
            run_tile(e, fr[0], fr[1], fr[2], fr[3],
                     v[4], w[4], v[5], w[5], fr[6], fr[7], i & 1);
        }
    }
}

extern "C" void kernel_launch(void* const* d_in, const int* in_sizes, int n_in,
                              void* d_out, int out_size, void* d_ws, size_t ws_size,
                              hipStream_t stream) {
    const float* x_s        = (const float*)d_in[0];
    const float* x_t        = (const float*)d_in[1];
    const int*   edge_index = (const int*)d_in[2];   // harness: integer -> int32
    const float* edge_attr  = (const float*)d_in[3];
    const float* ug         = (const float*)d_in[4];
    const int*   batch_e    = (const int*)d_in[5];
    const float* W1         = (const float*)d_in[6];
    const float* b1         = (const float*)d_in[7];
    const float* W2         = (const float*)d_in[8];
    const float* b2         = (const float*)d_in[9];
    float*       out        = (float*)d_out;

    if (ws_size >= (size_t)WS_BYTES) {
        __bf16* tbl = (__bf16*)d_ws;
        prep_tables<<<(int)((WS_ELEMS / 8 + 255) / 256), 256, 0, stream>>>(x_s, x_t, ug, tbl);
        edge_mlp_kernel<true><<<NBLOCKS, 256, 0, stream>>>(
            x_s, x_t, edge_index, edge_attr, ug, batch_e, W1, b1, W2, b2, tbl, out);
    } else {
        edge_mlp_kernel<false><<<NBLOCKS, 256, 0, stream>>>(
            x_s, x_t, edge_index, edge_attr, ug, batch_e, W1, b1, W2, b2, nullptr, out);
    }
}

// Round 13
// 136.932 us; speedup vs baseline: 1.0457x; 1.0457x over previous
//
#include <hip/hip_runtime.h>
#include <hip/hip_bf16.h>

typedef __attribute__((ext_vector_type(8))) __bf16 bf16x8;
typedef __attribute__((ext_vector_type(4))) float f32x4;

#define N_EDGES 800000
#define N_TILES 50000            // 16-edge tiles
#define WAVES 8                  // 512-thread blocks
#define TPW 5
#define NBLOCKS 1250             // 1250 * 8 * 5 = 50000 exactly

#define XS_OFF 0LL
#define XT_OFF 3200000LL         // 50000*64
#define U_OFF  6400000LL
#define WS_ELEMS 6408192LL       // + 128*64
#define WS_BYTES (WS_ELEMS * 2)

// ---- prep: convert gather tables x_s | x_t | u to bf16 in ws (r9-verified) ----
__global__ void prep_tables(const float* __restrict__ x_s,
                            const float* __restrict__ x_t,
                            const float* __restrict__ ug,
                            __bf16* __restrict__ ws) {
    long long i = (long long)(blockIdx.x * 256 + threadIdx.x) * 8;
    if (i >= WS_ELEMS) return;
    const float* src = (i < XT_OFF) ? (x_s + i)
                     : (i < U_OFF)  ? (x_t + (i - XT_OFF))
                                    : (ug  + (i - U_OFF));
    float4 f0 = *(const float4*)src;
    float4 f1 = *(const float4*)(src + 4);
    bf16x8 o;
    o[0] = (__bf16)f0.x; o[1] = (__bf16)f0.y; o[2] = (__bf16)f0.z; o[3] = (__bf16)f0.w;
    o[4] = (__bf16)f1.x; o[5] = (__bf16)f1.y; o[6] = (__bf16)f1.z; o[7] = (__bf16)f1.w;
    *(bf16x8*)(ws + i) = o;
}

__device__ __forceinline__ void gload16(const void* g, void* l) {
    __builtin_amdgcn_global_load_lds(
        (const __attribute__((address_space(1))) void*)g,
        (__attribute__((address_space(3))) void*)l, 16, 0, 0);
}

template<bool BF>
__global__ __launch_bounds__(512, 2) void edge_mlp_kernel(
    const float* __restrict__ x_s, const float* __restrict__ x_t,
    const int* __restrict__ edge_index, const float* __restrict__ edge_attr,
    const float* __restrict__ ug, const int* __restrict__ batch_e,
    const float* __restrict__ W1, const float* __restrict__ b1,
    const float* __restrict__ W2, const float* __restrict__ b2,
    const __bf16* __restrict__ tbl,
    float* __restrict__ out)
{
    // LDS: 32768 + 8*2048 + 8*3*4096 = 147456 -> 1 block/CU (8 waves/CU)
    __shared__ __align__(16) unsigned char sW1[32768];        // [n1][k] bf16, XOR-swz
    __shared__ __align__(16) unsigned char sH1[WAVES][2048];  // [16e][64n1] bf16, XOR-swz
    __shared__ __align__(16) unsigned char sRing[WAVES][3][4096]; // 3-deep DMA ring

    const int t = threadIdx.x;

    for (int idx = t; idx < 256 * 64; idx += 512) {
        int k = idx >> 6, n = idx & 63;
        *(__bf16*)(sW1 + n * 512 + ((k * 2) ^ ((n & 7) << 4))) = (__bf16)W1[idx];
    }
    __syncthreads();

    const int wave = t >> 6;
    const int lane = t & 63;
    const int l15  = lane & 15;
    const int lk   = lane >> 4;
    const int wxor = (l15 & 7) << 4;

    float bv1[4];
    #pragma unroll
    for (int nf = 0; nf < 4; ++nf) bv1[nf] = b1[nf * 16 + l15];
    f32x4 bias2frag[4];
    #pragma unroll
    for (int mf = 0; mf < 4; ++mf)
        #pragma unroll
        for (int r = 0; r < 4; ++r)
            bias2frag[mf][r] = b2[mf * 16 + lk * 4 + r];

    // ---- W2^T A-fragments in 16 VGPRs (tile-invariant; r10-verified) ----
    bf16x8 aw2[2][4];
    #pragma unroll
    for (int kk2 = 0; kk2 < 2; ++kk2)
        #pragma unroll
        for (int mf = 0; mf < 4; ++mf)
            #pragma unroll
            for (int r = 0; r < 8; ++r)
                aw2[kk2][mf][r] = (__bf16)W2[(kk2 * 32 + lk * 8 + r) * 64 + mf * 16 + l15];

    const int tile_base = (blockIdx.x * WAVES + wave) * TPW;

    int bgs[TPW];
    int ss_lo[TPW], ss_hi[TPW], tt_lo[TPW], tt_hi[TPW];
    #pragma unroll
    for (int i = 0; i < TPW; ++i) {
        const int e = (tile_base + i) * 16 + l15;
        const int sv = edge_index[e];
        const int tv = edge_index[N_EDGES + e];
        bgs[i]  = batch_e[e];
        ss_lo[i] = __shfl(sv, lane >> 3);
        ss_hi[i] = __shfl(sv, 8 + (lane >> 3));
        tt_lo[i] = __shfl(tv, lane >> 3);
        tt_hi[i] = __shfl(tv, 8 + (lane >> 3));
    }
    // pre-swizzled source elem offset (r10-verified; rule 21)
    const int swzel = ((((lane & 7) << 4) ^ (((lane >> 3) & 7) << 4)) >> 1);

#define ISSUE_DMA(j, rb) do {                                          \
    gload16(tbl + XS_OFF + (long long)ss_lo[j] * 64 + swzel, (rb));    \
    gload16(tbl + XS_OFF + (long long)ss_hi[j] * 64 + swzel, (rb) + 1024); \
    gload16(tbl + XT_OFF + (long long)tt_lo[j] * 64 + swzel, (rb) + 2048); \
    gload16(tbl + XT_OFF + (long long)tt_hi[j] * 64 + swzel, (rb) + 3072); \
} while (0)

    if (BF) {
        f32x4  pea[2][4];
        bf16x8 pu[2][2];

        // ---- prologue: D_0, D_1 (dist-2 ring), then P_0 (ea/u tile 0) ----
        ISSUE_DMA(0, &sRing[wave][0][0]);
        ISSUE_DMA(1, &sRing[wave][1][0]);
        {
            const float* pe = edge_attr + (long long)(tile_base * 16 + l15) * 64 + lk * 8;
            pea[0][0] = *(const f32x4*)(pe);
            pea[0][1] = *(const f32x4*)(pe + 4);
            pea[0][2] = *(const f32x4*)(pe + 32);
            pea[0][3] = *(const f32x4*)(pe + 36);
            const __bf16* up = tbl + U_OFF + (long long)bgs[0] * 64 + lk * 8;
            pu[0][0] = *(const bf16x8*)(up);
            pu[0][1] = *(const bf16x8*)(up + 32);
        }
        __builtin_amdgcn_sched_barrier(0);

        #pragma unroll
        for (int i = 0; i < TPW; ++i) {
            const int e   = (tile_base + i) * 16 + l15;
            const int cur = i & 1, nxt = (i + 1) & 1;

            // ---- P_{i+1}: ea/u prefetch into the other reg buffer ----
            if (i + 1 < TPW) {
                const float* pe = edge_attr + (long long)((tile_base + i + 1) * 16 + l15) * 64 + lk * 8;
                pea[nxt][0] = *(const f32x4*)(pe);
                pea[nxt][1] = *(const f32x4*)(pe + 4);
                pea[nxt][2] = *(const f32x4*)(pe + 32);
                pea[nxt][3] = *(const f32x4*)(pe + 36);
                const __bf16* up = tbl + U_OFF + (long long)bgs[i + 1] * 64 + lk * 8;
                pu[nxt][0] = *(const bf16x8*)(up);
                pu[nxt][1] = *(const bf16x8*)(up + 32);
            }
            __builtin_amdgcn_sched_barrier(0);

            // ---- D_{i+2}: DMA into ring[(i+2)%3] ----
            if (i + 2 < TPW)
                ISSUE_DMA(i + 2, &sRing[wave][(i + 2) % 3][0]);
            __builtin_amdgcn_sched_barrier(0);

            // ---- wait: P_i done (transitively D_i done; in-order vmcnt) ----
            // younger sets: i=0: P1(6)+D2(4)=10; i=1,2: D(4)+S(4)+P(6)+D(4)=18;
            //               i=3: D4(4)+S2(4)+P4(6)=14; i=4: S3(4)=4
            if      (i == 0) asm volatile("s_waitcnt vmcnt(10)" ::: "memory");
            else if (i <= 2) asm volatile("s_waitcnt vmcnt(18)" ::: "memory");
            else if (i == 3) asm volatile("s_waitcnt vmcnt(14)" ::: "memory");
            else             asm volatile("s_waitcnt vmcnt(4)"  ::: "memory");
            __builtin_amdgcn_sched_barrier(0);

            // ---- ring -> regs (swizzled reads; r10-verified) ----
            const unsigned char* rbuf = &sRing[wave][i % 3][0];
            const int o0 = l15 * 128 + ((0 * 64 + lk * 16) ^ wxor);
            const int o1 = l15 * 128 + ((64 + lk * 16) ^ wxor);
            bf16x8 r0 = *(const bf16x8*)(rbuf + o0);
            bf16x8 r1 = *(const bf16x8*)(rbuf + o1);
            bf16x8 r2 = *(const bf16x8*)(rbuf + 2048 + o0);
            bf16x8 r3 = *(const bf16x8*)(rbuf + 2048 + o1);

            // ---- GEMM1: bias folded ----
            f32x4 acc[4];
            #pragma unroll
            for (int nf = 0; nf < 4; ++nf)
                acc[nf] = (f32x4){bv1[nf], bv1[nf], bv1[nf], bv1[nf]};
            #pragma unroll
            for (int kk = 0; kk < 8; ++kk) {
                bf16x8 a;
                if      (kk == 0) a = r0;
                else if (kk == 1) a = r1;
                else if (kk == 2) a = r2;
                else if (kk == 3) a = r3;
                else if (kk == 4) {
                    #pragma unroll
                    for (int r = 0; r < 4; ++r) { a[r] = (__bf16)pea[cur][0][r]; a[4+r] = (__bf16)pea[cur][1][r]; }
                } else if (kk == 5) {
                    #pragma unroll
                    for (int r = 0; r < 4; ++r) { a[r] = (__bf16)pea[cur][2][r]; a[4+r] = (__bf16)pea[cur][3][r]; }
                } else a = (kk == 6) ? pu[cur][0] : pu[cur][1];
                #pragma unroll
                for (int nf = 0; nf < 4; ++nf) {
                    bf16x8 b = *(const bf16x8*)(sW1 + (nf * 16 + l15) * 512 +
                                                ((kk * 64 + lk * 16) ^ wxor));
                    acc[nf] = __builtin_amdgcn_mfma_f32_16x16x32_bf16(a, b, acc[nf], 0, 0, 0);
                }
            }

            // ---- LeakyReLU -> bf16 -> sH1 (swizzled; r12-verified) ----
            unsigned char* hb = &sH1[wave][0];
            #pragma unroll
            for (int nf = 0; nf < 4; ++nf)
                #pragma unroll
                for (int r = 0; r < 4; ++r) {
                    float v = acc[nf][r];
                    v = fmaxf(v, 0.1f * v);
                    const int row = lk * 4 + r, col = nf * 16 + l15;
                    *(__bf16*)(hb + row * 128 + ((col * 2) ^ ((row & 7) << 4))) = (__bf16)v;
                }

            // ---- GEMM2^T (aw2 in regs) ----
            f32x4 acc2[4];
            #pragma unroll
            for (int mf = 0; mf < 4; ++mf) acc2[mf] = bias2frag[mf];
            #pragma unroll
            for (int kk2 = 0; kk2 < 2; ++kk2) {
                bf16x8 bh = *(const bf16x8*)(hb + l15 * 128 +
                                             ((kk2 * 64 + lk * 16) ^ ((l15 & 7) << 4)));
                #pragma unroll
                for (int mf = 0; mf < 4; ++mf)
                    acc2[mf] = __builtin_amdgcn_mfma_f32_16x16x32_bf16(aw2[kk2][mf], bh, acc2[mf], 0, 0, 0);
            }

            // ---- stores: S_i (4 dwordx4) ----
            float* orow = out + (long long)e * 64;
            #pragma unroll
            for (int mf = 0; mf < 4; ++mf)
                *(f32x4*)&orow[mf * 16 + lk * 4] = acc2[mf];
        }
    } else {
        // fallback: direct fp32 gathers (no ws). Correctness path only.
        for (int i = 0; i < TPW; ++i) {
            const int e = (tile_base + i) * 16 + l15;
            const int sv = edge_index[e];
            const int tv = edge_index[N_EDGES + e];
            const int bg = batch_e[e];
            f32x4 acc[4];
            #pragma unroll
            for (int nf = 0; nf < 4; ++nf)
                acc[nf] = (f32x4){bv1[nf], bv1[nf], bv1[nf], bv1[nf]};
            #pragma unroll
            for (int kk = 0; kk < 8; ++kk) {
                const int k0 = kk * 32 + lk * 8;
                const float* p =
                    (k0 < 64)  ? (x_s + (long long)sv * 64 + k0) :
                    (k0 < 128) ? (x_t + (long long)tv * 64 + (k0 - 64)) :
                    (k0 < 192) ? (edge_attr + (long long)e * 64 + (k0 - 128)) :
                                 (ug + (long long)bg * 64 + (k0 - 192));
                float4 f0 = *(const float4*)p;
                float4 f1 = *(const float4*)(p + 4);
                bf16x8 a;
                a[0]=(__bf16)f0.x; a[1]=(__bf16)f0.y; a[2]=(__bf16)f0.z; a[3]=(__bf16)f0.w;
                a[4]=(__bf16)f1.x; a[5]=(__bf16)f1.y; a[6]=(__bf16)f1.z; a[7]=(__bf16)f1.w;
                #pragma unroll
                for (int nf = 0; nf < 4; ++nf) {
                    bf16x8 b = *(const bf16x8*)(sW1 + (nf * 16 + l15) * 512 +
                                                ((kk * 64 + lk * 16) ^ wxor));
                    acc[nf] = __builtin_amdgcn_mfma_f32_16x16x32_bf16(a, b, acc[nf], 0, 0, 0);
                }
            }
            unsigned char* hb = &sH1[wave][0];
            #pragma unroll
            for (int nf = 0; nf < 4; ++nf)
                #pragma unroll
                for (int r = 0; r < 4; ++r) {
                    float v = acc[nf][r];
                    v = fmaxf(v, 0.1f * v);
                    const int row = lk * 4 + r, col = nf * 16 + l15;
                    *(__bf16*)(hb + row * 128 + ((col * 2) ^ ((row & 7) << 4))) = (__bf16)v;
                }
            f32x4 acc2[4];
            #pragma unroll
            for (int mf = 0; mf < 4; ++mf) acc2[mf] = bias2frag[mf];
            #pragma unroll
            for (int kk2 = 0; kk2 < 2; ++kk2) {
                bf16x8 bh = *(const bf16x8*)(hb + l15 * 128 +
                                             ((kk2 * 64 + lk * 16) ^ ((l15 & 7) << 4)));
                #pragma unroll
                for (int mf = 0; mf < 4; ++mf)
                    acc2[mf] = __builtin_amdgcn_mfma_f32_16x16x32_bf16(aw2[kk2][mf], bh, acc2[mf], 0, 0, 0);
            }
            float* orow = out + (long long)e * 64;
            #pragma unroll
            for (int mf = 0; mf < 4; ++mf)
                *(f32x4*)&orow[mf * 16 + lk * 4] = acc2[mf];
        }
    }
#undef ISSUE_DMA
}

extern "C" void kernel_launch(void* const* d_in, const int* in_sizes, int n_in,
                              void* d_out, int out_size, void* d_ws, size_t ws_size,
                              hipStream_t stream) {
    const float* x_s        = (const float*)d_in[0];
    const float* x_t        = (const float*)d_in[1];
    const int*   edge_index = (const int*)d_in[2];   // harness: integer -> int32
    const float* edge_attr  = (const float*)d_in[3];
    const float* ug         = (const float*)d_in[4];
    const int*   batch_e    = (const int*)d_in[5];
    const float* W1         = (const float*)d_in[6];
    const float* b1         = (const float*)d_in[7];
    const float* W2         = (const float*)d_in[8];
    const float* b2         = (const float*)d_in[9];
    float*       out        = (float*)d_out;

    if (ws_size >= (size_t)WS_BYTES) {
        __bf16* tbl = (__bf16*)d_ws;
        prep_tables<<<(int)((WS_ELEMS / 8 + 255) / 256), 256, 0, stream>>>(x_s, x_t, ug, tbl);
        edge_mlp_kernel<true><<<NBLOCKS, 512, 0, stream>>>(
            x_s, x_t, edge_index, edge_attr, ug, batch_e, W1, b1, W2, b2, tbl, out);
    } else {
        edge_mlp_kernel<false><<<NBLOCKS, 512, 0, stream>>>(
            x_s, x_t, edge_index, edge_attr, ug, batch_e, W1, b1, W2, b2, nullptr, out);
    }
}

// Round 14
// 134.767 us; speedup vs baseline: 1.0625x; 1.0161x over previous
//
#include <hip/hip_runtime.h>
#include <hip/hip_bf16.h>

typedef __attribute__((ext_vector_type(8))) __bf16 bf16x8;
typedef __attribute__((ext_vector_type(4))) float f32x4;

#define N_NODES 50000
#define N_EDGES 800000
#define N_TILES 50000            // 16-edge tiles
#define WAVES 4
#define TPW 5
#define NBLOCKS 2500             // 2500*4*5 = 50000

#define P_OFF 0LL                // bf16 elems
#define Q_OFF 3200000LL          // 50000*64
#define R_BYTE 12800000LL        // f32 128x64
#define WS_NEED (12800000LL + 32768LL)

#define PB 782                   // blocks per table in prep_pq (ceil(3125/4))

// ==== prep 1: P = x_s@W1a + b1, Q = x_t@W1b  (bf16 tables, MFMA) ====
__global__ __launch_bounds__(256) void prep_pq(
    const float* __restrict__ x_s, const float* __restrict__ x_t,
    const float* __restrict__ W1, const float* __restrict__ b1,
    __bf16* __restrict__ ws)
{
    __shared__ __align__(16) unsigned char sW[8192];     // [n][k] bf16 swz
    __shared__ __align__(16) unsigned char sH[4][2048];  // C->row-major staging

    const int t = threadIdx.x;
    const bool isQ = (int)blockIdx.x >= PB;
    const float* X = isQ ? x_t : x_s;
    const int wrow0 = isQ ? 64 : 0;
    __bf16* dst = ws + (isQ ? Q_OFF : P_OFF);

    for (int idx = t; idx < 64 * 64; idx += 256) {
        int k = idx >> 6, n = idx & 63;
        *(__bf16*)(sW + n * 128 + ((k * 2) ^ ((n & 7) << 4))) =
            (__bf16)W1[(wrow0 + k) * 64 + n];
    }
    __syncthreads();

    const int wave = t >> 6, lane = t & 63, l15 = lane & 15, lk = lane >> 4;
    const int wxor = (l15 & 7) << 4;
    const int tile = ((int)blockIdx.x % PB) * 4 + wave;  // 16-node tile
    if (tile >= 3125) return;

    float bv[4];
    #pragma unroll
    for (int nf = 0; nf < 4; ++nf) bv[nf] = isQ ? 0.f : b1[nf * 16 + l15];

    const int row = tile * 16 + l15;
    const float* xr = X + (long long)row * 64 + lk * 8;
    f32x4 v0 = *(const f32x4*)(xr);
    f32x4 v1 = *(const f32x4*)(xr + 4);
    f32x4 v2 = *(const f32x4*)(xr + 32);
    f32x4 v3 = *(const f32x4*)(xr + 36);
    bf16x8 a0, a1;
    #pragma unroll
    for (int r = 0; r < 4; ++r) {
        a0[r] = (__bf16)v0[r]; a0[4+r] = (__bf16)v1[r];
        a1[r] = (__bf16)v2[r]; a1[4+r] = (__bf16)v3[r];
    }

    f32x4 acc[4];
    #pragma unroll
    for (int nf = 0; nf < 4; ++nf) acc[nf] = (f32x4){bv[nf], bv[nf], bv[nf], bv[nf]};
    #pragma unroll
    for (int kk = 0; kk < 2; ++kk) {
        bf16x8 a = (kk == 0) ? a0 : a1;
        #pragma unroll
        for (int nf = 0; nf < 4; ++nf) {
            bf16x8 b = *(const bf16x8*)(sW + (nf * 16 + l15) * 128 +
                                        ((kk * 64 + lk * 16) ^ wxor));
            acc[nf] = __builtin_amdgcn_mfma_f32_16x16x32_bf16(a, b, acc[nf], 0, 0, 0);
        }
    }

    // C-layout -> swizzled LDS -> coalesced row-major bf16 store
    unsigned char* hb = &sH[wave][0];
    #pragma unroll
    for (int nf = 0; nf < 4; ++nf)
        #pragma unroll
        for (int r = 0; r < 4; ++r) {
            const int rr = lk * 4 + r, col = nf * 16 + l15;
            *(__bf16*)(hb + rr * 128 + ((col * 2) ^ ((rr & 7) << 4))) = (__bf16)acc[nf][r];
        }
    // same-wave RAW: compiler inserts lgkmcnt
    const int rr = lane >> 2, j = lane & 3;
    bf16x8 o0 = *(const bf16x8*)(hb + rr * 128 + ((j * 32) ^ ((rr & 7) << 4)));
    bf16x8 o1 = *(const bf16x8*)(hb + rr * 128 + (((j * 32) + 16) ^ ((rr & 7) << 4)));
    __bf16* drow = dst + (long long)(tile * 16 + rr) * 64 + j * 16;
    *(bf16x8*)(drow)     = o0;
    *(bf16x8*)(drow + 8) = o1;
}

// ==== prep 2: R = u@W1d (f32, 128x64) ====
__global__ void prep_r(const float* __restrict__ u, const float* __restrict__ W1,
                       float* __restrict__ Rf) {
    int o = blockIdx.x * 256 + threadIdx.x;
    if (o >= 128 * 64) return;
    int n = o >> 6, c = o & 63;
    float acc = 0.f;
    #pragma unroll 8
    for (int k = 0; k < 64; ++k)
        acc += u[n * 64 + k] * W1[(192 + k) * 64 + c];
    Rf[o] = acc;
}

__device__ __forceinline__ void gload16(const void* g, void* l) {
    __builtin_amdgcn_global_load_lds(
        (const __attribute__((address_space(1))) void*)g,
        (__attribute__((address_space(3))) void*)l, 16, 0, 0);
}

// ==== main: per-edge  h = P[src]+Q[tgt]+R[bg]+ea@W1c ; out = relu(h)@W2+b2 ====
__global__ __launch_bounds__(256, 3) void edge_mlp_kernel(
    const int* __restrict__ edge_index, const float* __restrict__ edge_attr,
    const int* __restrict__ batch_e,
    const float* __restrict__ W1, const float* __restrict__ W2,
    const float* __restrict__ b2,
    const __bf16* __restrict__ tbl, const float* __restrict__ Rf,
    float* __restrict__ out)
{
    // LDS: 8192 (W1c) + 4*2048 (sH1) + 4*2*4096 (ring) = 49152 -> 3 blocks/CU
    __shared__ __align__(16) unsigned char sW1c[8192];          // [n1][kc] bf16 swz
    __shared__ __align__(16) unsigned char sH1[WAVES][2048];    // [16e][64] bf16 swz
    __shared__ __align__(16) unsigned char sRing[WAVES][2][4096]; // [P|Q][16 rows][128B]

    const int t = threadIdx.x;
    for (int idx = t; idx < 64 * 64; idx += 256) {
        int k = idx >> 6, n = idx & 63;
        *(__bf16*)(sW1c + n * 128 + ((k * 2) ^ ((n & 7) << 4))) =
            (__bf16)W1[(128 + k) * 64 + n];
    }
    __syncthreads();

    const int wave = t >> 6, lane = t & 63, l15 = lane & 15, lk = lane >> 4;
    const int wxor = (l15 & 7) << 4;

    f32x4 bias2frag[4];
    #pragma unroll
    for (int mf = 0; mf < 4; ++mf)
        #pragma unroll
        for (int r = 0; r < 4; ++r)
            bias2frag[mf][r] = b2[mf * 16 + lk * 4 + r];

    // W2^T A-fragments in 16 VGPRs (r10-verified)
    bf16x8 aw2[2][4];
    #pragma unroll
    for (int kk2 = 0; kk2 < 2; ++kk2)
        #pragma unroll
        for (int mf = 0; mf < 4; ++mf)
            #pragma unroll
            for (int r = 0; r < 8; ++r)
                aw2[kk2][mf][r] = (__bf16)W2[(kk2 * 32 + lk * 8 + r) * 64 + mf * 16 + l15];

    const int tile_base = (blockIdx.x * WAVES + wave) * TPW;

    int bgs[TPW];
    int ss_lo[TPW], ss_hi[TPW], tt_lo[TPW], tt_hi[TPW];
    #pragma unroll
    for (int i = 0; i < TPW; ++i) {
        const int e = (tile_base + i) * 16 + l15;
        const int sv = edge_index[e];
        const int tv = edge_index[N_EDGES + e];
        bgs[i]  = batch_e[e];
        ss_lo[i] = __shfl(sv, lane >> 3);
        ss_hi[i] = __shfl(sv, 8 + (lane >> 3));
        tt_lo[i] = __shfl(tv, lane >> 3);
        tt_hi[i] = __shfl(tv, 8 + (lane >> 3));
    }
    const int swzel = ((((lane & 7) << 4) ^ (((lane >> 3) & 7) << 4)) >> 1);

#define ISSUE_DMA(j, rb) do {                                              \
    gload16(tbl + P_OFF + (long long)ss_lo[j] * 64 + swzel, (rb));         \
    gload16(tbl + P_OFF + (long long)ss_hi[j] * 64 + swzel, (rb) + 1024);  \
    gload16(tbl + Q_OFF + (long long)tt_lo[j] * 64 + swzel, (rb) + 2048);  \
    gload16(tbl + Q_OFF + (long long)tt_hi[j] * 64 + swzel, (rb) + 3072);  \
} while (0)

    // prologue: DMA tile 0
    ISSUE_DMA(0, &sRing[wave][0][0]);

    #pragma unroll
    for (int i = 0; i < TPW; ++i) {
        const int e = (tile_base + i) * 16 + l15;

        // ---- (a) ea loads + R loads ----
        const float* pe = edge_attr + (long long)e * 64 + lk * 8;
        f32x4 ev0 = *(const f32x4*)(pe);
        f32x4 ev1 = *(const f32x4*)(pe + 4);
        f32x4 ev2 = *(const f32x4*)(pe + 32);
        f32x4 ev3 = *(const f32x4*)(pe + 36);

        f32x4 acc[4];
        {
            const int b0 = __shfl(bgs[i], 0);
            if (__all(bgs[i] == b0)) {               // >99.7% of tiles
                #pragma unroll
                for (int nf = 0; nf < 4; ++nf) {
                    const float rv = Rf[b0 * 64 + nf * 16 + l15];
                    acc[nf] = (f32x4){rv, rv, rv, rv};
                }
            } else {
                int bgr[4];
                #pragma unroll
                for (int r = 0; r < 4; ++r) bgr[r] = __shfl(bgs[i], lk * 4 + r);
                #pragma unroll
                for (int nf = 0; nf < 4; ++nf)
                    #pragma unroll
                    for (int r = 0; r < 4; ++r)
                        acc[nf][r] = Rf[bgr[r] * 64 + nf * 16 + l15];
            }
        }
        __builtin_amdgcn_sched_barrier(0);

        // ---- (b) DMA next tile ----
        if (i + 1 < TPW)
            ISSUE_DMA(i + 1, &sRing[wave][(i + 1) & 1][0]);
        __builtin_amdgcn_sched_barrier(0);

        // ---- (c) wait: drain everything except next-tile DMA ----
        if (i + 1 < TPW) asm volatile("s_waitcnt vmcnt(4)" ::: "memory");
        else             asm volatile("s_waitcnt vmcnt(0)" ::: "memory");
        __builtin_amdgcn_sched_barrier(0);

        // ---- (d) GEMM1': ea @ W1c  (K=64, 8 MFMA) ----
        bf16x8 a0, a1;
        #pragma unroll
        for (int r = 0; r < 4; ++r) {
            a0[r] = (__bf16)ev0[r]; a0[4+r] = (__bf16)ev1[r];
            a1[r] = (__bf16)ev2[r]; a1[4+r] = (__bf16)ev3[r];
        }
        #pragma unroll
        for (int kk = 0; kk < 2; ++kk) {
            bf16x8 a = (kk == 0) ? a0 : a1;
            #pragma unroll
            for (int nf = 0; nf < 4; ++nf) {
                bf16x8 b = *(const bf16x8*)(sW1c + (nf * 16 + l15) * 128 +
                                            ((kk * 64 + lk * 16) ^ wxor));
                acc[nf] = __builtin_amdgcn_mfma_f32_16x16x32_bf16(a, b, acc[nf], 0, 0, 0);
            }
        }

        // ---- (e) += P[src] + Q[tgt]  (scalar LDS reads, 2-way max) ----
        const unsigned char* rbuf = &sRing[wave][i & 1][0];
        #pragma unroll
        for (int nf = 0; nf < 4; ++nf)
            #pragma unroll
            for (int r = 0; r < 4; ++r) {
                const int erow = lk * 4 + r, col = nf * 16 + l15;
                const int off = erow * 128 + ((col * 2) ^ ((erow & 7) << 4));
                acc[nf][r] += (float)*(const __bf16*)(rbuf + off)
                            + (float)*(const __bf16*)(rbuf + 2048 + off);
            }

        // ---- (f) LeakyReLU -> bf16 -> sH1 (swizzled) ----
        unsigned char* hb = &sH1[wave][0];
        #pragma unroll
        for (int nf = 0; nf < 4; ++nf)
            #pragma unroll
            for (int r = 0; r < 4; ++r) {
                float v = acc[nf][r];
                v = fmaxf(v, 0.1f * v);
                const int row = lk * 4 + r, col = nf * 16 + l15;
                *(__bf16*)(hb + row * 128 + ((col * 2) ^ ((row & 7) << 4))) = (__bf16)v;
            }

        // ---- (g) GEMM2^T ----
        f32x4 acc2[4];
        #pragma unroll
        for (int mf = 0; mf < 4; ++mf) acc2[mf] = bias2frag[mf];
        #pragma unroll
        for (int kk2 = 0; kk2 < 2; ++kk2) {
            bf16x8 bh = *(const bf16x8*)(hb + l15 * 128 +
                                         ((kk2 * 64 + lk * 16) ^ ((l15 & 7) << 4)));
            #pragma unroll
            for (int mf = 0; mf < 4; ++mf)
                acc2[mf] = __builtin_amdgcn_mfma_f32_16x16x32_bf16(aw2[kk2][mf], bh, acc2[mf], 0, 0, 0);
        }

        // ---- (h) store ----
        float* orow = out + (long long)e * 64;
        #pragma unroll
        for (int mf = 0; mf < 4; ++mf)
            *(f32x4*)&orow[mf * 16 + lk * 4] = acc2[mf];
    }
#undef ISSUE_DMA
}

// ==== fallback (ws too small): r7-verified direct structure ====
__global__ __launch_bounds__(256) void edge_mlp_fallback(
    const float* __restrict__ x_s, const float* __restrict__ x_t,
    const int* __restrict__ edge_index, const float* __restrict__ edge_attr,
    const float* __restrict__ ug, const int* __restrict__ batch_e,
    const float* __restrict__ W1, const float* __restrict__ b1,
    const float* __restrict__ W2, const float* __restrict__ b2,
    float* __restrict__ out)
{
    __shared__ __align__(16) unsigned char sW1[32768];
    __shared__ __align__(16) unsigned char sW2[8192];
    __shared__ __align__(16) __bf16 sH1[4][16][76];
    const int t = threadIdx.x;
    for (int idx = t; idx < 256 * 64; idx += 256) {
        int k = idx >> 6, n = idx & 63;
        *(__bf16*)(sW1 + n * 512 + ((k * 2) ^ ((n & 7) << 4))) = (__bf16)W1[idx];
    }
    for (int idx = t; idx < 64 * 64; idx += 256) {
        int k = idx >> 6, n = idx & 63;
        *(__bf16*)(sW2 + n * 128 + ((k * 2) ^ ((n & 7) << 4))) = (__bf16)W2[idx];
    }
    __syncthreads();
    const int wave = t >> 6, lane = t & 63, l15 = lane & 15, lk = lane >> 4;
    const int wxor = (l15 & 7) << 4;
    float bv1[4];
    #pragma unroll
    for (int nf = 0; nf < 4; ++nf) bv1[nf] = b1[nf * 16 + l15];
    f32x4 b2f[4];
    #pragma unroll
    for (int mf = 0; mf < 4; ++mf)
        #pragma unroll
        for (int r = 0; r < 4; ++r) b2f[mf][r] = b2[mf * 16 + lk * 4 + r];
    const int tile_base = (blockIdx.x * 4 + wave) * 8;
    for (int i = 0; i < 8; ++i) {
        const int tile = tile_base + i;
        if (tile >= N_TILES) break;
        const int e = tile * 16 + l15;
        const int sv = edge_index[e], tv = edge_index[N_EDGES + e], bg = batch_e[e];
        f32x4 acc[4];
        #pragma unroll
        for (int nf = 0; nf < 4; ++nf) acc[nf] = (f32x4){bv1[nf], bv1[nf], bv1[nf], bv1[nf]};
        #pragma unroll
        for (int kk = 0; kk < 8; ++kk) {
            const int k0 = kk * 32 + lk * 8;
            const float* p = (k0 < 64)  ? (x_s + (long long)sv * 64 + k0)
                           : (k0 < 128) ? (x_t + (long long)tv * 64 + (k0 - 64))
                           : (k0 < 192) ? (edge_attr + (long long)e * 64 + (k0 - 128))
                                        : (ug + (long long)bg * 64 + (k0 - 192));
            float4 f0 = *(const float4*)p, f1 = *(const float4*)(p + 4);
            bf16x8 a;
            a[0]=(__bf16)f0.x; a[1]=(__bf16)f0.y; a[2]=(__bf16)f0.z; a[3]=(__bf16)f0.w;
            a[4]=(__bf16)f1.x; a[5]=(__bf16)f1.y; a[6]=(__bf16)f1.z; a[7]=(__bf16)f1.w;
            #pragma unroll
            for (int nf = 0; nf < 4; ++nf) {
                bf16x8 b = *(const bf16x8*)(sW1 + (nf * 16 + l15) * 512 +
                                            ((kk * 64 + lk * 16) ^ wxor));
                acc[nf] = __builtin_amdgcn_mfma_f32_16x16x32_bf16(a, b, acc[nf], 0, 0, 0);
            }
        }
        #pragma unroll
        for (int nf = 0; nf < 4; ++nf)
            #pragma unroll
            for (int r = 0; r < 4; ++r) {
                float v = acc[nf][r];
                v = fmaxf(v, 0.1f * v);
                sH1[wave][lk * 4 + r][nf * 16 + l15] = (__bf16)v;
            }
        f32x4 acc2[4];
        #pragma unroll
        for (int mf = 0; mf < 4; ++mf) acc2[mf] = b2f[mf];
        #pragma unroll
        for (int kk2 = 0; kk2 < 2; ++kk2) {
            bf16x8 bh = *(const bf16x8*)&sH1[wave][l15][kk2 * 32 + lk * 8];
            #pragma unroll
            for (int mf = 0; mf < 4; ++mf) {
                bf16x8 aw = *(const bf16x8*)(sW2 + (mf * 16 + l15) * 128 +
                                             ((kk2 * 64 + lk * 16) ^ wxor));
                acc2[mf] = __builtin_amdgcn_mfma_f32_16x16x32_bf16(aw, bh, acc2[mf], 0, 0, 0);
            }
        }
        float* orow = out + (long long)e * 64;
        #pragma unroll
        for (int mf = 0; mf < 4; ++mf)
            *(f32x4*)&orow[mf * 16 + lk * 4] = acc2[mf];
    }
}

extern "C" void kernel_launch(void* const* d_in, const int* in_sizes, int n_in,
                              void* d_out, int out_size, void* d_ws, size_t ws_size,
                              hipStream_t stream) {
    const float* x_s        = (const float*)d_in[0];
    const float* x_t        = (const float*)d_in[1];
    const int*   edge_index = (const int*)d_in[2];   // harness: integer -> int32
    const float* edge_attr  = (const float*)d_in[3];
    const float* ug         = (const float*)d_in[4];
    const int*   batch_e    = (const int*)d_in[5];
    const float* W1         = (const float*)d_in[6];
    const float* b1         = (const float*)d_in[7];
    const float* W2         = (const float*)d_in[8];
    const float* b2         = (const float*)d_in[9];
    float*       out        = (float*)d_out;

    if (ws_size >= (size_t)WS_NEED) {
        __bf16* tbl = (__bf16*)d_ws;
        float*  Rf  = (float*)((unsigned char*)d_ws + R_BYTE);
        prep_pq<<<2 * PB, 256, 0, stream>>>(x_s, x_t, W1, b1, tbl);
        prep_r<<<32, 256, 0, stream>>>(ug, W1, Rf);
        edge_mlp_kernel<<<NBLOCKS, 256, 0, stream>>>(
            edge_index, edge_attr, batch_e, W1, W2, b2, tbl, Rf, out);
    } else {
        edge_mlp_fallback<<<(N_TILES + 31) / 32, 256, 0, stream>>>(
            x_s, x_t, edge_index, edge_attr, ug, batch_e, W1, b1, W2, b2, out);
    }
}

// Round 15
// 131.387 us; speedup vs baseline: 1.0898x; 1.0257x over previous
//
#include <hip/hip_runtime.h>
#include <hip/hip_bf16.h>

typedef __attribute__((ext_vector_type(8))) __bf16 bf16x8;
typedef __attribute__((ext_vector_type(4))) float f32x4;

#define N_NODES 50000
#define N_EDGES 800000
#define N_TILES 50000            // 16-edge tiles
#define WAVES 4
#define NBLOCKS 768              // 256 CU x 3 resident -> single generation

#define P_OFF 0LL                // bf16 elems
#define Q_OFF 3200000LL          // 50000*64
#define R_BYTE 12800000LL        // f32 128x64
#define WS_NEED (12800000LL + 32768LL)

#define PB 782                   // blocks per table in prep_pq (ceil(3125/4))

// ==== prep 1: P = x_s@W1a + b1, Q = x_t@W1b  (bf16 tables, MFMA; r14-verified) ====
__global__ __launch_bounds__(256) void prep_pq(
    const float* __restrict__ x_s, const float* __restrict__ x_t,
    const float* __restrict__ W1, const float* __restrict__ b1,
    __bf16* __restrict__ ws)
{
    __shared__ __align__(16) unsigned char sW[8192];     // [n][k] bf16 swz
    __shared__ __align__(16) unsigned char sH[4][2048];  // C->row-major staging

    const int t = threadIdx.x;
    const bool isQ = (int)blockIdx.x >= PB;
    const float* X = isQ ? x_t : x_s;
    const int wrow0 = isQ ? 64 : 0;
    __bf16* dst = ws + (isQ ? Q_OFF : P_OFF);

    for (int idx = t; idx < 64 * 64; idx += 256) {
        int k = idx >> 6, n = idx & 63;
        *(__bf16*)(sW + n * 128 + ((k * 2) ^ ((n & 7) << 4))) =
            (__bf16)W1[(wrow0 + k) * 64 + n];
    }
    __syncthreads();

    const int wave = t >> 6, lane = t & 63, l15 = lane & 15, lk = lane >> 4;
    const int wxor = (l15 & 7) << 4;
    const int tile = ((int)blockIdx.x % PB) * 4 + wave;  // 16-node tile
    if (tile >= 3125) return;

    float bv[4];
    #pragma unroll
    for (int nf = 0; nf < 4; ++nf) bv[nf] = isQ ? 0.f : b1[nf * 16 + l15];

    const int row = tile * 16 + l15;
    const float* xr = X + (long long)row * 64 + lk * 8;
    f32x4 v0 = *(const f32x4*)(xr);
    f32x4 v1 = *(const f32x4*)(xr + 4);
    f32x4 v2 = *(const f32x4*)(xr + 32);
    f32x4 v3 = *(const f32x4*)(xr + 36);
    bf16x8 a0, a1;
    #pragma unroll
    for (int r = 0; r < 4; ++r) {
        a0[r] = (__bf16)v0[r]; a0[4+r] = (__bf16)v1[r];
        a1[r] = (__bf16)v2[r]; a1[4+r] = (__bf16)v3[r];
    }

    f32x4 acc[4];
    #pragma unroll
    for (int nf = 0; nf < 4; ++nf) acc[nf] = (f32x4){bv[nf], bv[nf], bv[nf], bv[nf]};
    #pragma unroll
    for (int kk = 0; kk < 2; ++kk) {
        bf16x8 a = (kk == 0) ? a0 : a1;
        #pragma unroll
        for (int nf = 0; nf < 4; ++nf) {
            bf16x8 b = *(const bf16x8*)(sW + (nf * 16 + l15) * 128 +
                                        ((kk * 64 + lk * 16) ^ wxor));
            acc[nf] = __builtin_amdgcn_mfma_f32_16x16x32_bf16(a, b, acc[nf], 0, 0, 0);
        }
    }

    unsigned char* hb = &sH[wave][0];
    #pragma unroll
    for (int nf = 0; nf < 4; ++nf)
        #pragma unroll
        for (int r = 0; r < 4; ++r) {
            const int rr = lk * 4 + r, col = nf * 16 + l15;
            *(__bf16*)(hb + rr * 128 + ((col * 2) ^ ((rr & 7) << 4))) = (__bf16)acc[nf][r];
        }
    const int rr = lane >> 2, j = lane & 3;
    bf16x8 o0 = *(const bf16x8*)(hb + rr * 128 + ((j * 32) ^ ((rr & 7) << 4)));
    bf16x8 o1 = *(const bf16x8*)(hb + rr * 128 + (((j * 32) + 16) ^ ((rr & 7) << 4)));
    __bf16* drow = dst + (long long)(tile * 16 + rr) * 64 + j * 16;
    *(bf16x8*)(drow)     = o0;
    *(bf16x8*)(drow + 8) = o1;
}

// ==== prep 2: R = u@W1d (f32, 128x64) ====
__global__ void prep_r(const float* __restrict__ u, const float* __restrict__ W1,
                       float* __restrict__ Rf) {
    int o = blockIdx.x * 256 + threadIdx.x;
    if (o >= 128 * 64) return;
    int n = o >> 6, c = o & 63;
    float acc = 0.f;
    #pragma unroll 8
    for (int k = 0; k < 64; ++k)
        acc += u[n * 64 + k] * W1[(192 + k) * 64 + c];
    Rf[o] = acc;
}

__device__ __forceinline__ void gload16(const void* g, void* l) {
    __builtin_amdgcn_global_load_lds(
        (const __attribute__((address_space(1))) void*)g,
        (__attribute__((address_space(3))) void*)l, 16, 0, 0);
}

// ==== main: persistent waves, contiguous tile runs, r14 body ====
__global__ __launch_bounds__(256, 3) void edge_mlp_kernel(
    const int* __restrict__ edge_index, const float* __restrict__ edge_attr,
    const int* __restrict__ batch_e,
    const float* __restrict__ W1, const float* __restrict__ W2,
    const float* __restrict__ b2,
    const __bf16* __restrict__ tbl, const float* __restrict__ Rf,
    float* __restrict__ out)
{
    // LDS: 8192 (W1c) + 4*2048 (sH1) + 4*2*4096 (ring) = 49152 -> 3 blocks/CU
    __shared__ __align__(16) unsigned char sW1c[8192];
    __shared__ __align__(16) unsigned char sH1[WAVES][2048];
    __shared__ __align__(16) unsigned char sRing[WAVES][2][4096];

    const int t = threadIdx.x;
    for (int idx = t; idx < 64 * 64; idx += 256) {
        int k = idx >> 6, n = idx & 63;
        *(__bf16*)(sW1c + n * 128 + ((k * 2) ^ ((n & 7) << 4))) =
            (__bf16)W1[(128 + k) * 64 + n];
    }
    __syncthreads();

    const int wave = t >> 6, lane = t & 63, l15 = lane & 15, lk = lane >> 4;
    const int wxor = (l15 & 7) << 4;

    f32x4 bias2frag[4];
    #pragma unroll
    for (int mf = 0; mf < 4; ++mf)
        #pragma unroll
        for (int r = 0; r < 4; ++r)
            bias2frag[mf][r] = b2[mf * 16 + lk * 4 + r];

    bf16x8 aw2[2][4];
    #pragma unroll
    for (int kk2 = 0; kk2 < 2; ++kk2)
        #pragma unroll
        for (int mf = 0; mf < 4; ++mf)
            #pragma unroll
            for (int r = 0; r < 8; ++r)
                aw2[kk2][mf][r] = (__bf16)W2[(kk2 * 32 + lk * 8 + r) * 64 + mf * 16 + l15];

    // persistent-wave tile range: 848 waves x 17 + 2224 x 16 = 50000
    const int w = (int)blockIdx.x * WAVES + wave;
    const int nt = 16 + (w < 848 ? 1 : 0);
    const int tstart = w * 16 + (w < 848 ? w : 848);

    const int swzel = ((((lane & 7) << 4) ^ (((lane >> 3) & 7) << 4)) >> 1);

#define ISSUE_DMA_V(sv, tv, rb) do {                                       \
    int _slo = __shfl((sv), lane >> 3);                                    \
    int _shi = __shfl((sv), 8 + (lane >> 3));                              \
    int _tlo = __shfl((tv), lane >> 3);                                    \
    int _thi = __shfl((tv), 8 + (lane >> 3));                              \
    gload16(tbl + P_OFF + (long long)_slo * 64 + swzel, (rb));             \
    gload16(tbl + P_OFF + (long long)_shi * 64 + swzel, (rb) + 1024);      \
    gload16(tbl + Q_OFF + (long long)_tlo * 64 + swzel, (rb) + 2048);      \
    gload16(tbl + Q_OFF + (long long)_thi * 64 + swzel, (rb) + 3072);      \
} while (0)

    // ---- prologue: DMA tile 0; preload idx of tile 1 (nt >= 16 always) ----
    int bgC;
    {
        const int e0 = tstart * 16 + l15;
        const int sv0 = edge_index[e0];
        const int tv0 = edge_index[N_EDGES + e0];
        bgC = batch_e[e0];
        ISSUE_DMA_V(sv0, tv0, &sRing[wave][0][0]);
    }
    int svD, tvD, bgD, svP = 0, tvP = 0, bgP = 0;
    {
        const int e1 = (tstart + 1) * 16 + l15;
        svD = edge_index[e1];
        tvD = edge_index[N_EDGES + e1];
        bgD = batch_e[e1];
    }

    for (int i = 0; i < nt; ++i) {
        const int e = (tstart + i) * 16 + l15;

        // ---- (a) ea loads + R init (fast path: wave-uniform graph) ----
        const float* pe = edge_attr + (long long)e * 64 + lk * 8;
        f32x4 ev0 = *(const f32x4*)(pe);
        f32x4 ev1 = *(const f32x4*)(pe + 4);
        f32x4 ev2 = *(const f32x4*)(pe + 32);
        f32x4 ev3 = *(const f32x4*)(pe + 36);

        f32x4 acc[4];
        {
            const int b0 = __shfl(bgC, 0);
            if (__all(bgC == b0)) {
                #pragma unroll
                for (int nf = 0; nf < 4; ++nf) {
                    const float rv = Rf[b0 * 64 + nf * 16 + l15];
                    acc[nf] = (f32x4){rv, rv, rv, rv};
                }
            } else {
                int bgr[4];
                #pragma unroll
                for (int r = 0; r < 4; ++r) bgr[r] = __shfl(bgC, lk * 4 + r);
                #pragma unroll
                for (int nf = 0; nf < 4; ++nf)
                    #pragma unroll
                    for (int r = 0; r < 4; ++r)
                        acc[nf][r] = Rf[bgr[r] * 64 + nf * 16 + l15];
            }
        }
        __builtin_amdgcn_sched_barrier(0);

        // ---- (b) DMA tile i+1; load idx tile i+2 ----
        if (i + 1 < nt) {
            ISSUE_DMA_V(svD, tvD, &sRing[wave][(i + 1) & 1][0]);
            if (i + 2 < nt) {
                const int e2 = (tstart + i + 2) * 16 + l15;
                svP = edge_index[e2];
                tvP = edge_index[N_EDGES + e2];
                bgP = batch_e[e2];
            }
        }
        __builtin_amdgcn_sched_barrier(0);

        // ---- (c) counted wait (in-order vmcnt): leave DMA(4)+idx(3) in flight ----
        if      (i + 2 < nt) asm volatile("s_waitcnt vmcnt(7)" ::: "memory");
        else if (i + 1 < nt) asm volatile("s_waitcnt vmcnt(4)" ::: "memory");
        else                 asm volatile("s_waitcnt vmcnt(0)" ::: "memory");
        __builtin_amdgcn_sched_barrier(0);

        // ---- (d) GEMM1': ea @ W1c (K=64, 8 MFMA) ----
        bf16x8 a0, a1;
        #pragma unroll
        for (int r = 0; r < 4; ++r) {
            a0[r] = (__bf16)ev0[r]; a0[4+r] = (__bf16)ev1[r];
            a1[r] = (__bf16)ev2[r]; a1[4+r] = (__bf16)ev3[r];
        }
        #pragma unroll
        for (int kk = 0; kk < 2; ++kk) {
            bf16x8 a = (kk == 0) ? a0 : a1;
            #pragma unroll
            for (int nf = 0; nf < 4; ++nf) {
                bf16x8 b = *(const bf16x8*)(sW1c + (nf * 16 + l15) * 128 +
                                            ((kk * 64 + lk * 16) ^ wxor));
                acc[nf] = __builtin_amdgcn_mfma_f32_16x16x32_bf16(a, b, acc[nf], 0, 0, 0);
            }
        }

        // ---- (e) += P[src] + Q[tgt] (scalar LDS reads; r14-verified) ----
        const unsigned char* rbuf = &sRing[wave][i & 1][0];
        #pragma unroll
        for (int nf = 0; nf < 4; ++nf)
            #pragma unroll
            for (int r = 0; r < 4; ++r) {
                const int erow = lk * 4 + r, col = nf * 16 + l15;
                const int off = erow * 128 + ((col * 2) ^ ((erow & 7) << 4));
                acc[nf][r] += (float)*(const __bf16*)(rbuf + off)
                            + (float)*(const __bf16*)(rbuf + 2048 + off);
            }

        // ---- (f) LeakyReLU -> bf16 -> sH1 (swizzled) ----
        unsigned char* hb = &sH1[wave][0];
        #pragma unroll
        for (int nf = 0; nf < 4; ++nf)
            #pragma unroll
            for (int r = 0; r < 4; ++r) {
                float v = acc[nf][r];
                v = fmaxf(v, 0.1f * v);
                const int row = lk * 4 + r, col = nf * 16 + l15;
                *(__bf16*)(hb + row * 128 + ((col * 2) ^ ((row & 7) << 4))) = (__bf16)v;
            }

        // ---- (g) GEMM2^T ----
        f32x4 acc2[4];
        #pragma unroll
        for (int mf = 0; mf < 4; ++mf) acc2[mf] = bias2frag[mf];
        #pragma unroll
        for (int kk2 = 0; kk2 < 2; ++kk2) {
            bf16x8 bh = *(const bf16x8*)(hb + l15 * 128 +
                                         ((kk2 * 64 + lk * 16) ^ ((l15 & 7) << 4)));
            #pragma unroll
            for (int mf = 0; mf < 4; ++mf)
                acc2[mf] = __builtin_amdgcn_mfma_f32_16x16x32_bf16(aw2[kk2][mf], bh, acc2[mf], 0, 0, 0);
        }

        // ---- (h) store ----
        float* orow = out + (long long)e * 64;
        #pragma unroll
        for (int mf = 0; mf < 4; ++mf)
            *(f32x4*)&orow[mf * 16 + lk * 4] = acc2[mf];

        // ---- rotate rolling index state ----
        bgC = bgD; svD = svP; tvD = tvP; bgD = bgP;
    }
#undef ISSUE_DMA_V
}

// ==== fallback (ws too small): r7-verified direct structure ====
__global__ __launch_bounds__(256) void edge_mlp_fallback(
    const float* __restrict__ x_s, const float* __restrict__ x_t,
    const int* __restrict__ edge_index, const float* __restrict__ edge_attr,
    const float* __restrict__ ug, const int* __restrict__ batch_e,
    const float* __restrict__ W1, const float* __restrict__ b1,
    const float* __restrict__ W2, const float* __restrict__ b2,
    float* __restrict__ out)
{
    __shared__ __align__(16) unsigned char sW1[32768];
    __shared__ __align__(16) unsigned char sW2[8192];
    __shared__ __align__(16) __bf16 sH1[4][16][76];
    const int t = threadIdx.x;
    for (int idx = t; idx < 256 * 64; idx += 256) {
        int k = idx >> 6, n = idx & 63;
        *(__bf16*)(sW1 + n * 512 + ((k * 2) ^ ((n & 7) << 4))) = (__bf16)W1[idx];
    }
    for (int idx = t; idx < 64 * 64; idx += 256) {
        int k = idx >> 6, n = idx & 63;
        *(__bf16*)(sW2 + n * 128 + ((k * 2) ^ ((n & 7) << 4))) = (__bf16)W2[idx];
    }
    __syncthreads();
    const int wave = t >> 6, lane = t & 63, l15 = lane & 15, lk = lane >> 4;
    const int wxor = (l15 & 7) << 4;
    float bv1[4];
    #pragma unroll
    for (int nf = 0; nf < 4; ++nf) bv1[nf] = b1[nf * 16 + l15];
    f32x4 b2f[4];
    #pragma unroll
    for (int mf = 0; mf < 4; ++mf)
        #pragma unroll
        for (int r = 0; r < 4; ++r) b2f[mf][r] = b2[mf * 16 + lk * 4 + r];
    const int tile_base = (blockIdx.x * 4 + wave) * 8;
    for (int i = 0; i < 8; ++i) {
        const int tile = tile_base + i;
        if (tile >= N_TILES) break;
        const int e = tile * 16 + l15;
        const int sv = edge_index[e], tv = edge_index[N_EDGES + e], bg = batch_e[e];
        f32x4 acc[4];
        #pragma unroll
        for (int nf = 0; nf < 4; ++nf) acc[nf] = (f32x4){bv1[nf], bv1[nf], bv1[nf], bv1[nf]};
        #pragma unroll
        for (int kk = 0; kk < 8; ++kk) {
            const int k0 = kk * 32 + lk * 8;
            const float* p = (k0 < 64)  ? (x_s + (long long)sv * 64 + k0)
                           : (k0 < 128) ? (x_t + (long long)tv * 64 + (k0 - 64))
                           : (k0 < 192) ? (edge_attr + (long long)e * 64 + (k0 - 128))
                                        : (ug + (long long)bg * 64 + (k0 - 192));
            float4 f0 = *(const float4*)p, f1 = *(const float4*)(p + 4);
            bf16x8 a;
            a[0]=(__bf16)f0.x; a[1]=(__bf16)f0.y; a[2]=(__bf16)f0.z; a[3]=(__bf16)f0.w;
            a[4]=(__bf16)f1.x; a[5]=(__bf16)f1.y; a[6]=(__bf16)f1.z; a[7]=(__bf16)f1.w;
            #pragma unroll
            for (int nf = 0; nf < 4; ++nf) {
                bf16x8 b = *(const bf16x8*)(sW1 + (nf * 16 + l15) * 512 +
                                            ((kk * 64 + lk * 16) ^ wxor));
                acc[nf] = __builtin_amdgcn_mfma_f32_16x16x32_bf16(a, b, acc[nf], 0, 0, 0);
            }
        }
        #pragma unroll
        for (int nf = 0; nf < 4; ++nf)
            #pragma unroll
            for (int r = 0; r < 4; ++r) {
                float v = acc[nf][r];
                v = fmaxf(v, 0.1f * v);
                sH1[wave][lk * 4 + r][nf * 16 + l15] = (__bf16)v;
            }
        f32x4 acc2[4];
        #pragma unroll
        for (int mf = 0; mf < 4; ++mf) acc2[mf] = b2f[mf];
        #pragma unroll
        for (int kk2 = 0; kk2 < 2; ++kk2) {
            bf16x8 bh = *(const bf16x8*)&sH1[wave][l15][kk2 * 32 + lk * 8];
            #pragma unroll
            for (int mf = 0; mf < 4; ++mf) {
                bf16x8 aw = *(const bf16x8*)(sW2 + (mf * 16 + l15) * 128 +
                                             ((kk2 * 64 + lk * 16) ^ wxor));
                acc2[mf] = __builtin_amdgcn_mfma_f32_16x16x32_bf16(aw, bh, acc2[mf], 0, 0, 0);
            }
        }
        float* orow = out + (long long)e * 64;
        #pragma unroll
        for (int mf = 0; mf < 4; ++mf)
            *(f32x4*)&orow[mf * 16 + lk * 4] = acc2[mf];
    }
}

extern "C" void kernel_launch(void* const* d_in, const int* in_sizes, int n_in,
                              void* d_out, int out_size, void* d_ws, size_t ws_size,
                              hipStream_t stream) {
    const float* x_s        = (const float*)d_in[0];
    const float* x_t        = (const float*)d_in[1];
    const int*   edge_index = (const int*)d_in[2];   // harness: integer -> int32
    const float* edge_attr  = (const float*)d_in[3];
    const float* ug         = (const float*)d_in[4];
    const int*   batch_e    = (const int*)d_in[5];
    const float* W1         = (const float*)d_in[6];
    const float* b1         = (const float*)d_in[7];
    const float* W2         = (const float*)d_in[8];
    const float* b2         = (const float*)d_in[9];
    float*       out        = (float*)d_out;

    if (ws_size >= (size_t)WS_NEED) {
        __bf16* tbl = (__bf16*)d_ws;
        float*  Rf  = (float*)((unsigned char*)d_ws + R_BYTE);
        prep_pq<<<2 * PB, 256, 0, stream>>>(x_s, x_t, W1, b1, tbl);
        prep_r<<<32, 256, 0, stream>>>(ug, W1, Rf);
        edge_mlp_kernel<<<NBLOCKS, 256, 0, stream>>>(
            edge_index, edge_attr, batch_e, W1, W2, b2, tbl, Rf, out);
    } else {
        edge_mlp_fallback<<<(N_TILES + 31) / 32, 256, 0, stream>>>(
            x_s, x_t, edge_index, edge_attr, ug, batch_e, W1, b1, W2, b2, out);
    }
}